// Round 1
// baseline (340.004 us; speedup 1.0000x reference)
//
#include <hip/hip_runtime.h>
#include <math.h>

#define NATOM 20000
#define NNBR  64
#define KM    64
#define KM3   (KM*KM*KM)

#define ALPHA_C 0.35f
#define KE_C    14.399645478425668f
#define TWO_OVER_SQRTPI 1.1283791670955126f
#define TWOPI_F 6.2831853071795864f
#define PI_F    3.14159265358979f

// scal layout (floats)
#define S_V     0
#define S_QTOT  1
#define S_SUMQ2 2
#define S_HINV  3   // 3..11 row-major inv(cell)
#define S_NSCAL 16

// workspace layout (float offsets)
#define WS_RE    0
#define WS_IM    (KM3)
#define WS_MESH  (2*KM3)
#define WS_GPOS  (3*KM3)             // 3*NATOM floats
#define WS_SCAL  (3*KM3 + 3*NATOM)
#define WS_CFAC  (WS_SCAL + S_NSCAL)
#define WS_PART  (WS_CFAC + KM)      // 64 slots * 16 fields
#define WS_TOTAL (WS_PART + 64*16)
// part fields: 0=e_real, 1..6=geps_real(xx,yy,zz,xy,xz,yz), 7=sE_rec, 8..13=sV

__device__ __forceinline__ float M2f(float x){ return fmaxf(0.f, 1.f - fabsf(x - 1.f)); }
__device__ __forceinline__ float M3f(float x){ return (x*M2f(x) + (3.f-x)*M2f(x-1.f)) * 0.5f; }
__device__ __forceinline__ float M4f(float x){ return (x*M3f(x) + (4.f-x)*M3f(x-1.f)) * (1.f/3.f); }

__device__ __forceinline__ float wsum64(float v){
#pragma unroll
  for(int off=32; off>0; off>>=1) v += __shfl_xor(v, off, 64);
  return v;
}

// ---------------- setup: Hinv, V, qtot, sum q^2, B-spline |b(m)|^-2 table ----
__global__ void setup_kernel(const float* __restrict__ q, const float* __restrict__ cell,
                             float* __restrict__ scal, float* __restrict__ cfac){
  __shared__ float s1[256], s2[256];
  int t = threadIdx.x;
  float a=0.f, b=0.f;
  for(int i=t;i<NATOM;i+=256){ float qi=q[i]; a+=qi; b+=qi*qi; }
  s1[t]=a; s2[t]=b; __syncthreads();
  for(int off=128; off>0; off>>=1){ if(t<off){ s1[t]+=s1[t+off]; s2[t]+=s2[t+off]; } __syncthreads(); }
  if(t==0){
    scal[S_QTOT]=s1[0]; scal[S_SUMQ2]=s2[0];
    float m00=cell[0],m01=cell[1],m02=cell[2];
    float m10=cell[3],m11=cell[4],m12=cell[5];
    float m20=cell[6],m21=cell[7],m22=cell[8];
    float det = m00*(m11*m22-m12*m21) - m01*(m10*m22-m12*m20) + m02*(m10*m21-m11*m20);
    float id = 1.f/det;
    scal[S_V] = fabsf(det);
    scal[S_HINV+0] = (m11*m22 - m12*m21)*id;
    scal[S_HINV+1] = (m02*m21 - m01*m22)*id;
    scal[S_HINV+2] = (m01*m12 - m02*m11)*id;
    scal[S_HINV+3] = (m12*m20 - m10*m22)*id;
    scal[S_HINV+4] = (m00*m22 - m02*m20)*id;
    scal[S_HINV+5] = (m02*m10 - m00*m12)*id;
    scal[S_HINV+6] = (m10*m21 - m11*m20)*id;
    scal[S_HINV+7] = (m01*m20 - m00*m21)*id;
    scal[S_HINV+8] = (m00*m11 - m01*m10)*id;
  }
  if(t < KM){
    // Mv = M4(1..3) = 1/6, 2/3, 1/6 ; b(m) = sum Mv[k] e^{2 pi i m k / K}
    const float Mv[3] = {1.f/6.f, 2.f/3.f, 1.f/6.f};
    float dre=0.f, dim=0.f;
#pragma unroll
    for(int k=0;k<3;k++){
      float ph = TWOPI_F * (float)t * (float)k / (float)KM;
      float s_, c_; sincosf(ph, &s_, &c_);
      dre += Mv[k]*c_; dim += Mv[k]*s_;
    }
    cfac[t] = 1.f/(dre*dre + dim*dim);
  }
}

// ---------------- real-space pair sum: one wave per atom ---------------------
__global__ __launch_bounds__(64) void real_kernel(const float* __restrict__ pos, const float* __restrict__ q,
                            const int* __restrict__ nbr, const int* __restrict__ shifts,
                            const float* __restrict__ cell,
                            float* __restrict__ gpos, float* __restrict__ part){
  int i = blockIdx.x;
  int l = threadIdx.x;
  float xi=pos[3*i], yi=pos[3*i+1], zi=pos[3*i+2], qi=q[i];
  int j = nbr[i*NNBR + l];
  int sb = (i*NNBR + l)*3;
  int sx=shifts[sb], sy=shifts[sb+1], sz=shifts[sb+2];
  bool valid = (j>=0) && !((j==i) && (sx==0 && sy==0 && sz==0));
  int jj = j>=0 ? j : 0;
  float rx = pos[3*jj]   - xi + sx*cell[0] + sy*cell[3] + sz*cell[6];
  float ry = pos[3*jj+1] - yi + sx*cell[1] + sy*cell[4] + sz*cell[7];
  float rz = pos[3*jj+2] - zi + sx*cell[2] + sy*cell[5] + sz*cell[8];
  float r2 = rx*rx + ry*ry + rz*rz;
  float e = 0.f, s = 0.f;
  if(valid && r2 > 0.f){
    float r = sqrtf(r2);
    float ar = ALPHA_C * r;
    if(ar < 9.f){   // erfc(9) ~ 4e-37: negligible beyond
      float qq = qi * q[jj];
      float ef = erfcf(ar);
      float ex = expf(-ar*ar);
      float inv_r = 1.f/r;
      e = 0.5f*qq*ef*inv_r;
      s = 0.5f*qq*(ef + TWO_OVER_SQRTPI*ar*ex)*inv_r*inv_r*inv_r;
    }
  }
  float gx = s*rx, gy = s*ry, gz = s*rz;      // dE/dpos_i contribution
  if(s != 0.f){                                // dE/dpos_j = -s*rvec (scatter)
    atomicAdd(&gpos[3*jj+0], -gx);
    atomicAdd(&gpos[3*jj+1], -gy);
    atomicAdd(&gpos[3*jj+2], -gz);
  }
  float vxx=-s*rx*rx, vyy=-s*ry*ry, vzz=-s*rz*rz;
  float vxy=-s*rx*ry, vxz=-s*rx*rz, vyz=-s*ry*rz;
  e = wsum64(e);
  gx = wsum64(gx); gy = wsum64(gy); gz = wsum64(gz);
  vxx = wsum64(vxx); vyy = wsum64(vyy); vzz = wsum64(vzz);
  vxy = wsum64(vxy); vxz = wsum64(vxz); vyz = wsum64(vyz);
  if(l==0){
    atomicAdd(&gpos[3*i+0], gx);
    atomicAdd(&gpos[3*i+1], gy);
    atomicAdd(&gpos[3*i+2], gz);
    float* slot = part + (blockIdx.x & 63)*16;
    atomicAdd(&slot[0], e);
    atomicAdd(&slot[1], vxx); atomicAdd(&slot[2], vyy); atomicAdd(&slot[3], vzz);
    atomicAdd(&slot[4], vxy); atomicAdd(&slot[5], vxz); atomicAdd(&slot[6], vyz);
  }
}

// ---------------- B-spline charge spreading ---------------------------------
__global__ void spread_kernel(const float* __restrict__ pos, const float* __restrict__ q,
                              const float* __restrict__ scal, float* __restrict__ mesh){
  int i = blockIdx.x*blockDim.x + threadIdx.x;
  if(i>=NATOM) return;
  float h0=scal[S_HINV+0],h1=scal[S_HINV+1],h2=scal[S_HINV+2];
  float h3=scal[S_HINV+3],h4=scal[S_HINV+4],h5=scal[S_HINV+5];
  float h6=scal[S_HINV+6],h7=scal[S_HINV+7],h8=scal[S_HINV+8];
  float px=pos[3*i], py=pos[3*i+1], pz=pos[3*i+2], qi=q[i];
  float u0=(px*h0+py*h3+pz*h6)*(float)KM;
  float u1=(px*h1+py*h4+pz*h7)*(float)KM;
  float u2=(px*h2+py*h5+pz*h8)*(float)KM;
  float b0=floorf(u0), b1=floorf(u1), b2=floorf(u2);
  float t0=u0-b0, t1=u1-b1, t2=u2-b2;
  int i0=(int)b0, i1=(int)b1, i2=(int)b2;
  float wx[4], wy[4], wz[4]; int ax[4], ay[4], az[4];
#pragma unroll
  for(int a=0;a<4;a++){
    float fa=(float)a;
    wx[a]=M4f(t0+fa); wy[a]=M4f(t1+fa); wz[a]=M4f(t2+fa);
    ax[a]=(i0-a+256)&63; ay[a]=(i1-a+256)&63; az[a]=(i2-a+256)&63;
  }
#pragma unroll
  for(int a=0;a<4;a++){
#pragma unroll
    for(int b=0;b<4;b++){
      float wab = qi*wx[a]*wy[b];
      int rb = (ax[a]*KM + ay[b])*KM;
#pragma unroll
      for(int c=0;c<4;c++)
        atomicAdd(&mesh[rb + az[c]], wab*wz[c]);
    }
  }
}

// ---------------- 64-point DFT pass along one axis (in-place per line) ------
__global__ __launch_bounds__(64) void dft_pass(float* __restrict__ re, float* __restrict__ im,
                         const float* __restrict__ src_real, int axis, float sgn){
  __shared__ float lre[64], lim[64], twr[64], twi[64];
  int l = blockIdx.x, t = threadIdx.x;
  int base, stride;
  if(axis==2){ base = l<<6;                       stride = 1;    }
  else if(axis==1){ base = ((l>>6)<<12) | (l&63); stride = 64;   }
  else { base = l;                                stride = 4096; }
  int idx = base + t*stride;
  if(src_real){ lre[t]=src_real[idx]; lim[t]=0.f; }
  else        { lre[t]=re[idx];       lim[t]=im[idx]; }
  float ss, cc;
  sincosf(sgn*(TWOPI_F/64.f)*(float)t, &ss, &cc);
  twr[t]=cc; twi[t]=ss;
  __syncthreads();
  float ar=0.f, ai=0.f;
#pragma unroll 8
  for(int z=0; z<64; z++){
    int k = (t*z)&63;
    float wr=twr[k], wi=twi[k], xr=lre[z], xi=lim[z];
    ar = fmaf(xr, wr, fmaf(-xi, wi, ar));
    ai = fmaf(xr, wi, fmaf( xi, wr, ai));
  }
  re[idx]=ar; im[idx]=ai;
}

// ---------------- k-space multiply + energy/virial reduction ----------------
__global__ void kmul_kernel(float* __restrict__ re, float* __restrict__ im,
                            const float* __restrict__ scal, const float* __restrict__ cfac,
                            float* __restrict__ part){
  float h0=scal[S_HINV+0],h1=scal[S_HINV+1],h2=scal[S_HINV+2];
  float h3=scal[S_HINV+3],h4=scal[S_HINV+4],h5=scal[S_HINV+5];
  float h6=scal[S_HINV+6],h7=scal[S_HINV+7],h8=scal[S_HINV+8];
  const float a2 = ALPHA_C*ALPHA_C;
  const float inv4a2 = 1.f/(4.f*a2);
  float sE=0.f, v0=0.f,v1=0.f,v2=0.f,v3=0.f,v4=0.f,v5=0.f;
  for(int idx = blockIdx.x*blockDim.x + threadIdx.x; idx < KM3; idx += gridDim.x*blockDim.x){
    int mz = idx & 63, my = (idx>>6) & 63, mx = idx>>12;
    float fx = (float)(mx<32 ? mx : mx-64);
    float fy = (float)(my<32 ? my : my-64);
    float fz = (float)(mz<32 ? mz : mz-64);
    float kx = TWOPI_F*(fx*h0 + fy*h1 + fz*h2);
    float ky = TWOPI_F*(fx*h3 + fy*h4 + fz*h5);
    float kz = TWOPI_F*(fx*h6 + fy*h7 + fz*h8);
    float k2 = kx*kx + ky*ky + kz*kz;
    float qr = re[idx], qi = im[idx];
    float w = 0.f;
    if(k2 > 0.f){
      float kern = expf(-k2*inv4a2)/k2;
      w = kern * cfac[mx]*cfac[my]*cfac[mz];
      float q2 = qr*qr + qi*qi;
      sE += w*q2;
      float fac = w*q2*(inv4a2 + 1.f/k2)*2.f;
      v0 += fac*kx*kx; v1 += fac*ky*ky; v2 += fac*kz*kz;
      v3 += fac*kx*ky; v4 += fac*kx*kz; v5 += fac*ky*kz;
    }
    re[idx] = w*qr; im[idx] = w*qi;
  }
  __shared__ float red[256];
  float vals[7] = {sE, v0, v1, v2, v3, v4, v5};
  float out7[7];
#pragma unroll
  for(int k=0;k<7;k++){
    red[threadIdx.x] = vals[k]; __syncthreads();
    for(int off=128; off>0; off>>=1){ if(threadIdx.x<off) red[threadIdx.x]+=red[threadIdx.x+off]; __syncthreads(); }
    out7[k]=red[0]; __syncthreads();
  }
  if(threadIdx.x==0){
    float* slot = part + (blockIdx.x & 63)*16;
    atomicAdd(&slot[7],  out7[0]);
#pragma unroll
    for(int k=0;k<6;k++) atomicAdd(&slot[8+k], out7[1+k]);
  }
}

// ---------------- force gather (reciprocal) + write forces ------------------
__global__ void gather_kernel(const float* __restrict__ pos, const float* __restrict__ q,
                              const float* __restrict__ scal, const float* __restrict__ phi,
                              const float* __restrict__ gpos, float* __restrict__ out){
  int i = blockIdx.x*blockDim.x + threadIdx.x;
  if(i>=NATOM) return;
  float h0=scal[S_HINV+0],h1=scal[S_HINV+1],h2=scal[S_HINV+2];
  float h3=scal[S_HINV+3],h4=scal[S_HINV+4],h5=scal[S_HINV+5];
  float h6=scal[S_HINV+6],h7=scal[S_HINV+7],h8=scal[S_HINV+8];
  float V = scal[S_V];
  float px=pos[3*i], py=pos[3*i+1], pz=pos[3*i+2], qi=q[i];
  float u0=(px*h0+py*h3+pz*h6)*(float)KM;
  float u1=(px*h1+py*h4+pz*h7)*(float)KM;
  float u2=(px*h2+py*h5+pz*h8)*(float)KM;
  float b0=floorf(u0), b1=floorf(u1), b2=floorf(u2);
  float t0=u0-b0, t1=u1-b1, t2=u2-b2;
  int i0=(int)b0, i1=(int)b1, i2=(int)b2;
  float wx[4], wy[4], wz[4], dx[4], dy[4], dz[4];
  int ax[4], ay[4], az[4];
#pragma unroll
  for(int a=0;a<4;a++){
    float fa=(float)a;
    wx[a]=M4f(t0+fa); wy[a]=M4f(t1+fa); wz[a]=M4f(t2+fa);
    dx[a]=M3f(t0+fa)-M3f(t0+fa-1.f);
    dy[a]=M3f(t1+fa)-M3f(t1+fa-1.f);
    dz[a]=M3f(t2+fa)-M3f(t2+fa-1.f);
    ax[a]=(i0-a+256)&63; ay[a]=(i1-a+256)&63; az[a]=(i2-a+256)&63;
  }
  float Sx=0.f, Sy=0.f, Sz=0.f;
#pragma unroll
  for(int a=0;a<4;a++){
#pragma unroll
    for(int b=0;b<4;b++){
      float wab = wx[a]*wy[b];
      float dab = dx[a]*wy[b];
      float wdb = wx[a]*dy[b];
      int rb = (ax[a]*KM + ay[b])*KM;
#pragma unroll
      for(int c=0;c<4;c++){
        float p = phi[rb + az[c]];
        Sx = fmaf(p, dab*wz[c], Sx);
        Sy = fmaf(p, wdb*wz[c], Sy);
        Sz = fmaf(p, wab*dz[c], Sz);
      }
    }
  }
  float scale = qi * (2.f*TWOPI_F/V) * (float)KM;  // 4*pi/V * K
  float g0 = scale*(Sx*h0 + Sy*h1 + Sz*h2);
  float g1 = scale*(Sx*h3 + Sy*h4 + Sz*h5);
  float g2 = scale*(Sx*h6 + Sy*h7 + Sz*h8);
  out[1+3*i+0] = -KE_C*(gpos[3*i+0] + g0);
  out[1+3*i+1] = -KE_C*(gpos[3*i+1] + g1);
  out[1+3*i+2] = -KE_C*(gpos[3*i+2] + g2);
}

// ---------------- finalize: energy + stress ---------------------------------
__global__ void finalize_kernel(const float* __restrict__ scal, const float* __restrict__ part,
                                float* __restrict__ out){
  if(threadIdx.x!=0 || blockIdx.x!=0) return;
  float acc[14];
  for(int k=0;k<14;k++) acc[k]=0.f;
  for(int s=0;s<64;s++)
    for(int k=0;k<14;k++) acc[k] += part[s*16+k];
  float V = scal[S_V], qtot = scal[S_QTOT], sumq2 = scal[S_SUMQ2];
  float a2 = ALPHA_C*ALPHA_C;
  float pref = TWOPI_F/V;
  float e_real = acc[0];
  float e_rec  = pref*acc[7];
  float e_self = -(ALPHA_C/sqrtf(PI_F))*sumq2;
  float e_bg   = -(PI_F/(2.f*a2*V))*qtot*qtot;
  out[0] = (e_real + e_rec + e_self + e_bg)*KE_C;
  float vs0=pref*acc[8], vs1=pref*acc[9], vs2=pref*acc[10];
  float vs3=pref*acc[11], vs4=pref*acc[12], vs5=pref*acc[13];
  float gxx = acc[1] + vs0 - e_rec - e_bg;
  float gyy = acc[2] + vs1 - e_rec - e_bg;
  float gzz = acc[3] + vs2 - e_rec - e_bg;
  float gxy = acc[4] + vs3, gxz = acc[5] + vs4, gyz = acc[6] + vs5;
  float c = -KE_C/V;    // stress = virial/V = -geps*KE/V
  float* st = out + 1 + 3*NATOM;
  st[0]=c*gxx; st[4]=c*gyy; st[8]=c*gzz;
  st[1]=c*gxy; st[3]=c*gxy;
  st[2]=c*gxz; st[6]=c*gxz;
  st[5]=c*gyz; st[7]=c*gyz;
}

extern "C" void kernel_launch(void* const* d_in, const int* in_sizes, int n_in,
                              void* d_out, int out_size, void* d_ws, size_t ws_size,
                              hipStream_t stream) {
  const float* pos  = (const float*)d_in[0];
  const float* q    = (const float*)d_in[1];
  const float* cell = (const float*)d_in[2];
  const int* nbr    = (const int*)d_in[3];
  const int* shifts = (const int*)d_in[4];
  float* out = (float*)d_out;
  float* ws  = (float*)d_ws;
  float* bufRe = ws + WS_RE;
  float* bufIm = ws + WS_IM;
  float* mesh  = ws + WS_MESH;
  float* gpos  = ws + WS_GPOS;
  float* scal  = ws + WS_SCAL;
  float* cfac  = ws + WS_CFAC;
  float* part  = ws + WS_PART;

  // zero mesh, gpos, scal, cfac, part in one contiguous memset
  hipMemsetAsync(mesh, 0, (size_t)(WS_TOTAL - WS_MESH)*sizeof(float), stream);
  setup_kernel<<<1,256,0,stream>>>(q, cell, scal, cfac);
  real_kernel<<<NATOM,64,0,stream>>>(pos,q,nbr,shifts,cell,gpos,part);
  spread_kernel<<<(NATOM+255)/256,256,0,stream>>>(pos,q,scal,mesh);
  dft_pass<<<4096,64,0,stream>>>(bufRe,bufIm,mesh,    2,-1.f);
  dft_pass<<<4096,64,0,stream>>>(bufRe,bufIm,nullptr, 1,-1.f);
  dft_pass<<<4096,64,0,stream>>>(bufRe,bufIm,nullptr, 0,-1.f);
  kmul_kernel<<<256,256,0,stream>>>(bufRe,bufIm,scal,cfac,part);
  dft_pass<<<4096,64,0,stream>>>(bufRe,bufIm,nullptr, 0, 1.f);
  dft_pass<<<4096,64,0,stream>>>(bufRe,bufIm,nullptr, 1, 1.f);
  dft_pass<<<4096,64,0,stream>>>(bufRe,bufIm,nullptr, 2, 1.f);
  gather_kernel<<<(NATOM+255)/256,256,0,stream>>>(pos,q,scal,bufRe,gpos,out);
  finalize_kernel<<<1,1,0,stream>>>(scal,part,out);
}

// Round 2
// 302.429 us; speedup vs baseline: 1.1242x; 1.1242x over previous
//
#include <hip/hip_runtime.h>
#include <math.h>

#define NATOM 20000
#define NNBR  64
#define KM    64
#define KM3   (KM*KM*KM)

#define ALPHA_C 0.35f
#define KE_C    14.399645478425668f
#define TWO_OVER_SQRTPI 1.1283791670955126f
#define TWOPI_F 6.2831853071795864f
#define PI_F    3.14159265358979f
#define RC2     661.2244898f   /* (9/alpha)^2 : erfc(9)~4e-37 beyond */

// scal layout (floats)
#define S_V     0
#define S_QTOT  1
#define S_SUMQ2 2
#define S_HINV  3   // 3..11 row-major inv(cell)
#define S_NSCAL 16

// workspace layout (float offsets)
#define WS_RE    0
#define WS_IM    (KM3)
#define WS_MESH  (2*KM3)
#define WS_FI    (3*KM3)                  // 3*NATOM, plain-stored (no init needed)
#define WS_GJ    (WS_FI + 3*NATOM)        // 3*NATOM, atomic scatter target (zeroed)
#define WS_SCAL  (WS_GJ + 3*NATOM)
#define WS_CFAC  (WS_SCAL + S_NSCAL)
#define WS_PART  (WS_CFAC + KM)           // 64 slots * 16 fields (zeroed)
#define WS_TOTAL (WS_PART + 64*16)
// part fields: 0=e_real, 1..6=geps_real(xx,yy,zz,xy,xz,yz), 7=sE_rec, 8..13=sV

__device__ __forceinline__ float M2f(float x){ return fmaxf(0.f, 1.f - fabsf(x - 1.f)); }
__device__ __forceinline__ float M3f(float x){ return (x*M2f(x) + (3.f-x)*M2f(x-1.f)) * 0.5f; }
__device__ __forceinline__ float M4f(float x){ return (x*M3f(x) + (4.f-x)*M3f(x-1.f)) * (1.f/3.f); }

__device__ __forceinline__ float wsum64(float v){
#pragma unroll
  for(int off=32; off>0; off>>=1) v += __shfl_xor(v, off, 64);
  return v;
}

// ---------------- setup: Hinv, V, qtot, sum q^2, B-spline |b(m)|^-2 table ----
__global__ void setup_kernel(const float* __restrict__ q, const float* __restrict__ cell,
                             float* __restrict__ scal, float* __restrict__ cfac){
  __shared__ float s1[256], s2[256];
  int t = threadIdx.x;
  float a=0.f, b=0.f;
  for(int i=t;i<NATOM;i+=256){ float qi=q[i]; a+=qi; b+=qi*qi; }
  s1[t]=a; s2[t]=b; __syncthreads();
  for(int off=128; off>0; off>>=1){ if(t<off){ s1[t]+=s1[t+off]; s2[t]+=s2[t+off]; } __syncthreads(); }
  if(t==0){
    scal[S_QTOT]=s1[0]; scal[S_SUMQ2]=s2[0];
    float m00=cell[0],m01=cell[1],m02=cell[2];
    float m10=cell[3],m11=cell[4],m12=cell[5];
    float m20=cell[6],m21=cell[7],m22=cell[8];
    float det = m00*(m11*m22-m12*m21) - m01*(m10*m22-m12*m20) + m02*(m10*m21-m11*m20);
    float id = 1.f/det;
    scal[S_V] = fabsf(det);
    scal[S_HINV+0] = (m11*m22 - m12*m21)*id;
    scal[S_HINV+1] = (m02*m21 - m01*m22)*id;
    scal[S_HINV+2] = (m01*m12 - m02*m11)*id;
    scal[S_HINV+3] = (m12*m20 - m10*m22)*id;
    scal[S_HINV+4] = (m00*m22 - m02*m20)*id;
    scal[S_HINV+5] = (m02*m10 - m00*m12)*id;
    scal[S_HINV+6] = (m10*m21 - m11*m20)*id;
    scal[S_HINV+7] = (m01*m20 - m00*m21)*id;
    scal[S_HINV+8] = (m00*m11 - m01*m10)*id;
  }
  if(t < KM){
    const float Mv[3] = {1.f/6.f, 2.f/3.f, 1.f/6.f};
    float dre=0.f, dim=0.f;
#pragma unroll
    for(int k=0;k<3;k++){
      float ph = TWOPI_F * (float)t * (float)k / (float)KM;
      float s_, c_; sincosf(ph, &s_, &c_);
      dre += Mv[k]*c_; dim += Mv[k]*s_;
    }
    cfac[t] = 1.f/(dre*dre + dim*dim);
  }
}

// ---------------- real-space pair sum: grid-stride waves, 4 atoms/wave ------
// 1250 blocks x 256 threads = 5000 waves; wave w handles atoms 4w..4w+3.
__global__ __launch_bounds__(256) void real_kernel(
    const float* __restrict__ pos, const float* __restrict__ q,
    const int* __restrict__ nbr, const int* __restrict__ shifts,
    const float* __restrict__ cell,
    float* __restrict__ fi, float* __restrict__ gj, float* __restrict__ part){
  int lane = threadIdx.x & 63;
  int wid  = blockIdx.x*4 + (threadIdx.x>>6);
  float c0=cell[0],c1=cell[1],c2=cell[2];
  float c3=cell[3],c4=cell[4],c5=cell[5];
  float c6=cell[6],c7=cell[7],c8=cell[8];
  float e=0.f, vxx=0.f,vyy=0.f,vzz=0.f,vxy=0.f,vxz=0.f,vyz=0.f;
#pragma unroll
  for(int it=0; it<4; ++it){
    int i = wid*4 + it;
    float xi=pos[3*i], yi=pos[3*i+1], zi=pos[3*i+2], qi=q[i];
    int p = i*NNBR + lane;
    int j = nbr[p];
    int sx=shifts[3*p], sy=shifts[3*p+1], sz=shifts[3*p+2];
    bool self = (j==i) && (sx==0) && (sy==0) && (sz==0);
    float s=0.f, rx=0.f, ry=0.f, rz=0.f;
    if(j>=0 && !self){
      rx = pos[3*j]   - xi + sx*c0 + sy*c3 + sz*c6;
      ry = pos[3*j+1] - yi + sx*c1 + sy*c4 + sz*c7;
      rz = pos[3*j+2] - zi + sx*c2 + sy*c5 + sz*c8;
      float r2 = rx*rx + ry*ry + rz*rz;
      if(r2 > 0.f && r2 < RC2){
        float r = sqrtf(r2);
        float ar = ALPHA_C * r;
        float qq = qi * q[j];
        float ef = erfcf(ar);
        float ex = expf(-ar*ar);
        float ir = 1.f/r;
        e += 0.5f*qq*ef*ir;
        s  = 0.5f*qq*(ef + TWO_OVER_SQRTPI*ar*ex)*ir*ir*ir;
      }
    }
    float gx = s*rx, gy = s*ry, gz = s*rz;
    if(s != 0.f){
      unsafeAtomicAdd(&gj[3*j+0], -gx);
      unsafeAtomicAdd(&gj[3*j+1], -gy);
      unsafeAtomicAdd(&gj[3*j+2], -gz);
    }
    vxx -= s*rx*rx; vyy -= s*ry*ry; vzz -= s*rz*rz;
    vxy -= s*rx*ry; vxz -= s*rx*rz; vyz -= s*ry*rz;
    float tgx = wsum64(gx), tgy = wsum64(gy), tgz = wsum64(gz);
    if(lane==0){ fi[3*i]=tgx; fi[3*i+1]=tgy; fi[3*i+2]=tgz; }
  }
  e   = wsum64(e);
  vxx = wsum64(vxx); vyy = wsum64(vyy); vzz = wsum64(vzz);
  vxy = wsum64(vxy); vxz = wsum64(vxz); vyz = wsum64(vyz);
  if(lane==0){
    float* slot = part + (wid & 63)*16;
    unsafeAtomicAdd(&slot[0], e);
    unsafeAtomicAdd(&slot[1], vxx); unsafeAtomicAdd(&slot[2], vyy); unsafeAtomicAdd(&slot[3], vzz);
    unsafeAtomicAdd(&slot[4], vxy); unsafeAtomicAdd(&slot[5], vxz); unsafeAtomicAdd(&slot[6], vyz);
  }
}

// ---------------- B-spline charge spreading ---------------------------------
__global__ void spread_kernel(const float* __restrict__ pos, const float* __restrict__ q,
                              const float* __restrict__ scal, float* __restrict__ mesh){
  int i = blockIdx.x*blockDim.x + threadIdx.x;
  if(i>=NATOM) return;
  float h0=scal[S_HINV+0],h1=scal[S_HINV+1],h2=scal[S_HINV+2];
  float h3=scal[S_HINV+3],h4=scal[S_HINV+4],h5=scal[S_HINV+5];
  float h6=scal[S_HINV+6],h7=scal[S_HINV+7],h8=scal[S_HINV+8];
  float px=pos[3*i], py=pos[3*i+1], pz=pos[3*i+2], qi=q[i];
  float u0=(px*h0+py*h3+pz*h6)*(float)KM;
  float u1=(px*h1+py*h4+pz*h7)*(float)KM;
  float u2=(px*h2+py*h5+pz*h8)*(float)KM;
  float b0=floorf(u0), b1=floorf(u1), b2=floorf(u2);
  float t0=u0-b0, t1=u1-b1, t2=u2-b2;
  int i0=(int)b0, i1=(int)b1, i2=(int)b2;
  float wx[4], wy[4], wz[4]; int ax[4], ay[4], az[4];
#pragma unroll
  for(int a=0;a<4;a++){
    float fa=(float)a;
    wx[a]=M4f(t0+fa); wy[a]=M4f(t1+fa); wz[a]=M4f(t2+fa);
    ax[a]=(i0-a+256)&63; ay[a]=(i1-a+256)&63; az[a]=(i2-a+256)&63;
  }
#pragma unroll
  for(int a=0;a<4;a++){
#pragma unroll
    for(int b=0;b<4;b++){
      float wab = qi*wx[a]*wy[b];
      int rb = (ax[a]*KM + ay[b])*KM;
#pragma unroll
      for(int c=0;c<4;c++)
        unsafeAtomicAdd(&mesh[rb + az[c]], wab*wz[c]);
    }
  }
}

// ---------------- DFT along z: 4 contiguous lines per 256-block -------------
__global__ __launch_bounds__(256) void dft_z(const float* __restrict__ srcr,
                       float* __restrict__ re, float* __restrict__ im, float sgn){
  __shared__ float tr[4][64], ti[4][64], twr[64], twi[64];
  int t = threadIdx.x;
  if(t < 64){
    float ss, cc; sincosf(sgn*(TWOPI_F/64.f)*(float)t, &ss, &cc);
    twr[t]=cc; twi[t]=ss;
  }
  int base = blockIdx.x*256;
  int line = t>>6, p = t&63;
  if(srcr){ tr[line][p]=srcr[base+t]; ti[line][p]=0.f; }
  else    { tr[line][p]=re[base+t];   ti[line][p]=im[base+t]; }
  __syncthreads();
  float ar=0.f, ai=0.f;
#pragma unroll 8
  for(int z=0; z<64; z++){
    int k = (p*z)&63;
    float wr=twr[k], wi=twi[k], xr=tr[line][z], xi=ti[line][z];
    ar = fmaf(xr, wr, fmaf(-xi, wi, ar));
    ai = fmaf(xr, wi, fmaf( xi, wr, ai));
  }
  re[base+t]=ar; im[base+t]=ai;
}

// ---------------- DFT along x or y: 64x16 LDS tile, coalesced ---------------
// axis==1: lines over y (stride 64), tile = fixed x, z in [z0,z0+16)
// axis==0: lines over x (stride 4096), tile = fixed y, z in [z0,z0+16)
__global__ __launch_bounds__(256) void dft_xy(float* __restrict__ re, float* __restrict__ im,
                                              int axis, float sgn){
  __shared__ float tr[64][17], ti[64][17], twr[64], twi[64];
  int t = threadIdx.x;
  if(t < 64){
    float ss, cc; sincosf(sgn*(TWOPI_F/64.f)*(float)t, &ss, &cc);
    twr[t]=cc; twi[t]=ss;
  }
  int stride = (axis==1) ? 64 : 4096;
  int base   = (axis==1) ? (int)(blockIdx.x>>2)*4096 + (int)(blockIdx.x&3)*16
                         : (int)(blockIdx.x>>2)*64   + (int)(blockIdx.x&3)*16;
#pragma unroll
  for(int k=0;k<4;k++){
    int e = k*256 + t;
    int li = e>>4, zz = e&15;
    int idx = base + li*stride + zz;
    tr[li][zz] = re[idx]; ti[li][zz] = im[idx];
  }
  __syncthreads();
#pragma unroll
  for(int k=0;k<4;k++){
    int e = k*256 + t;
    int lo = e>>4, zz = e&15;
    float ar=0.f, ai=0.f;
#pragma unroll 8
    for(int li=0; li<64; li++){
      int kk = (lo*li)&63;
      float wr=twr[kk], wi=twi[kk], xr=tr[li][zz], xi=ti[li][zz];
      ar = fmaf(xr, wr, fmaf(-xi, wi, ar));
      ai = fmaf(xr, wi, fmaf( xi, wr, ai));
    }
    int idx = base + lo*stride + zz;
    re[idx]=ar; im[idx]=ai;
  }
}

// ---------------- k-space multiply + energy/virial reduction ----------------
__global__ void kmul_kernel(float* __restrict__ re, float* __restrict__ im,
                            const float* __restrict__ scal, const float* __restrict__ cfac,
                            float* __restrict__ part){
  float h0=scal[S_HINV+0],h1=scal[S_HINV+1],h2=scal[S_HINV+2];
  float h3=scal[S_HINV+3],h4=scal[S_HINV+4],h5=scal[S_HINV+5];
  float h6=scal[S_HINV+6],h7=scal[S_HINV+7],h8=scal[S_HINV+8];
  const float a2 = ALPHA_C*ALPHA_C;
  const float inv4a2 = 1.f/(4.f*a2);
  float sE=0.f, v0=0.f,v1=0.f,v2=0.f,v3=0.f,v4=0.f,v5=0.f;
  for(int idx = blockIdx.x*blockDim.x + threadIdx.x; idx < KM3; idx += gridDim.x*blockDim.x){
    int mz = idx & 63, my = (idx>>6) & 63, mx = idx>>12;
    float fx = (float)(mx<32 ? mx : mx-64);
    float fy = (float)(my<32 ? my : my-64);
    float fz = (float)(mz<32 ? mz : mz-64);
    float kx = TWOPI_F*(fx*h0 + fy*h1 + fz*h2);
    float ky = TWOPI_F*(fx*h3 + fy*h4 + fz*h5);
    float kz = TWOPI_F*(fx*h6 + fy*h7 + fz*h8);
    float k2 = kx*kx + ky*ky + kz*kz;
    float qr = re[idx], qi = im[idx];
    float w = 0.f;
    if(k2 > 0.f){
      float kern = expf(-k2*inv4a2)/k2;
      w = kern * cfac[mx]*cfac[my]*cfac[mz];
      float q2 = qr*qr + qi*qi;
      sE += w*q2;
      float fac = w*q2*(inv4a2 + 1.f/k2)*2.f;
      v0 += fac*kx*kx; v1 += fac*ky*ky; v2 += fac*kz*kz;
      v3 += fac*kx*ky; v4 += fac*kx*kz; v5 += fac*ky*kz;
    }
    re[idx] = w*qr; im[idx] = w*qi;
  }
  __shared__ float red[256];
  float vals[7] = {sE, v0, v1, v2, v3, v4, v5};
  float out7[7];
#pragma unroll
  for(int k=0;k<7;k++){
    red[threadIdx.x] = vals[k]; __syncthreads();
    for(int off=128; off>0; off>>=1){ if(threadIdx.x<off) red[threadIdx.x]+=red[threadIdx.x+off]; __syncthreads(); }
    out7[k]=red[0]; __syncthreads();
  }
  if(threadIdx.x==0){
    float* slot = part + (blockIdx.x & 63)*16;
    unsafeAtomicAdd(&slot[7],  out7[0]);
#pragma unroll
    for(int k=0;k<6;k++) unsafeAtomicAdd(&slot[8+k], out7[1+k]);
  }
}

// ---------------- force gather (reciprocal) + write forces ------------------
__global__ void gather_kernel(const float* __restrict__ pos, const float* __restrict__ q,
                              const float* __restrict__ scal, const float* __restrict__ phi,
                              const float* __restrict__ fi, const float* __restrict__ gj,
                              float* __restrict__ out){
  int i = blockIdx.x*blockDim.x + threadIdx.x;
  if(i>=NATOM) return;
  float h0=scal[S_HINV+0],h1=scal[S_HINV+1],h2=scal[S_HINV+2];
  float h3=scal[S_HINV+3],h4=scal[S_HINV+4],h5=scal[S_HINV+5];
  float h6=scal[S_HINV+6],h7=scal[S_HINV+7],h8=scal[S_HINV+8];
  float V = scal[S_V];
  float px=pos[3*i], py=pos[3*i+1], pz=pos[3*i+2], qi=q[i];
  float u0=(px*h0+py*h3+pz*h6)*(float)KM;
  float u1=(px*h1+py*h4+pz*h7)*(float)KM;
  float u2=(px*h2+py*h5+pz*h8)*(float)KM;
  float b0=floorf(u0), b1=floorf(u1), b2=floorf(u2);
  float t0=u0-b0, t1=u1-b1, t2=u2-b2;
  int i0=(int)b0, i1=(int)b1, i2=(int)b2;
  float wx[4], wy[4], wz[4], dx[4], dy[4], dz[4];
  int ax[4], ay[4], az[4];
#pragma unroll
  for(int a=0;a<4;a++){
    float fa=(float)a;
    wx[a]=M4f(t0+fa); wy[a]=M4f(t1+fa); wz[a]=M4f(t2+fa);
    dx[a]=M3f(t0+fa)-M3f(t0+fa-1.f);
    dy[a]=M3f(t1+fa)-M3f(t1+fa-1.f);
    dz[a]=M3f(t2+fa)-M3f(t2+fa-1.f);
    ax[a]=(i0-a+256)&63; ay[a]=(i1-a+256)&63; az[a]=(i2-a+256)&63;
  }
  float Sx=0.f, Sy=0.f, Sz=0.f;
#pragma unroll
  for(int a=0;a<4;a++){
#pragma unroll
    for(int b=0;b<4;b++){
      float wab = wx[a]*wy[b];
      float dab = dx[a]*wy[b];
      float wdb = wx[a]*dy[b];
      int rb = (ax[a]*KM + ay[b])*KM;
#pragma unroll
      for(int c=0;c<4;c++){
        float p = phi[rb + az[c]];
        Sx = fmaf(p, dab*wz[c], Sx);
        Sy = fmaf(p, wdb*wz[c], Sy);
        Sz = fmaf(p, wab*dz[c], Sz);
      }
    }
  }
  float scale = qi * (2.f*TWOPI_F/V) * (float)KM;  // 2*pref*K
  float g0 = scale*(Sx*h0 + Sy*h1 + Sz*h2);
  float g1 = scale*(Sx*h3 + Sy*h4 + Sz*h5);
  float g2 = scale*(Sx*h6 + Sy*h7 + Sz*h8);
  out[1+3*i+0] = -KE_C*(fi[3*i+0] + gj[3*i+0] + g0);
  out[1+3*i+1] = -KE_C*(fi[3*i+1] + gj[3*i+1] + g1);
  out[1+3*i+2] = -KE_C*(fi[3*i+2] + gj[3*i+2] + g2);
}

// ---------------- finalize: energy + stress ---------------------------------
__global__ void finalize_kernel(const float* __restrict__ scal, const float* __restrict__ part,
                                float* __restrict__ out){
  if(threadIdx.x!=0 || blockIdx.x!=0) return;
  float acc[14];
  for(int k=0;k<14;k++) acc[k]=0.f;
  for(int s=0;s<64;s++)
    for(int k=0;k<14;k++) acc[k] += part[s*16+k];
  float V = scal[S_V], qtot = scal[S_QTOT], sumq2 = scal[S_SUMQ2];
  float a2 = ALPHA_C*ALPHA_C;
  float pref = TWOPI_F/V;
  float e_real = acc[0];
  float e_rec  = pref*acc[7];
  float e_self = -(ALPHA_C/sqrtf(PI_F))*sumq2;
  float e_bg   = -(PI_F/(2.f*a2*V))*qtot*qtot;
  out[0] = (e_real + e_rec + e_self + e_bg)*KE_C;
  float vs0=pref*acc[8], vs1=pref*acc[9], vs2=pref*acc[10];
  float vs3=pref*acc[11], vs4=pref*acc[12], vs5=pref*acc[13];
  float gxx = acc[1] + vs0 - e_rec - e_bg;
  float gyy = acc[2] + vs1 - e_rec - e_bg;
  float gzz = acc[3] + vs2 - e_rec - e_bg;
  float gxy = acc[4] + vs3, gxz = acc[5] + vs4, gyz = acc[6] + vs5;
  float c = -KE_C/V;    // stress = virial/V = -geps*KE/V
  float* st = out + 1 + 3*NATOM;
  st[0]=c*gxx; st[4]=c*gyy; st[8]=c*gzz;
  st[1]=c*gxy; st[3]=c*gxy;
  st[2]=c*gxz; st[6]=c*gxz;
  st[5]=c*gyz; st[7]=c*gyz;
}

extern "C" void kernel_launch(void* const* d_in, const int* in_sizes, int n_in,
                              void* d_out, int out_size, void* d_ws, size_t ws_size,
                              hipStream_t stream) {
  const float* pos  = (const float*)d_in[0];
  const float* q    = (const float*)d_in[1];
  const float* cell = (const float*)d_in[2];
  const int* nbr    = (const int*)d_in[3];
  const int* shifts = (const int*)d_in[4];
  float* out = (float*)d_out;
  float* ws  = (float*)d_ws;
  float* bufRe = ws + WS_RE;
  float* bufIm = ws + WS_IM;
  float* mesh  = ws + WS_MESH;
  float* fi    = ws + WS_FI;
  float* gj    = ws + WS_GJ;
  float* scal  = ws + WS_SCAL;
  float* cfac  = ws + WS_CFAC;
  float* part  = ws + WS_PART;

  // zero mesh, fi, gj, scal, cfac, part in one contiguous memset
  hipMemsetAsync(mesh, 0, (size_t)(WS_TOTAL - WS_MESH)*sizeof(float), stream);
  setup_kernel<<<1,256,0,stream>>>(q, cell, scal, cfac);
  real_kernel<<<1250,256,0,stream>>>(pos,q,nbr,shifts,cell,fi,gj,part);
  spread_kernel<<<(NATOM+255)/256,256,0,stream>>>(pos,q,scal,mesh);
  dft_z <<<1024,256,0,stream>>>(mesh, bufRe, bufIm, -1.f);
  dft_xy<<< 256,256,0,stream>>>(bufRe, bufIm, 1, -1.f);
  dft_xy<<< 256,256,0,stream>>>(bufRe, bufIm, 0, -1.f);
  kmul_kernel<<<256,256,0,stream>>>(bufRe,bufIm,scal,cfac,part);
  dft_xy<<< 256,256,0,stream>>>(bufRe, bufIm, 0,  1.f);
  dft_xy<<< 256,256,0,stream>>>(bufRe, bufIm, 1,  1.f);
  dft_z <<<1024,256,0,stream>>>(nullptr, bufRe, bufIm, 1.f);
  gather_kernel<<<(NATOM+255)/256,256,0,stream>>>(pos,q,scal,bufRe,fi,gj,out);
  finalize_kernel<<<1,1,0,stream>>>(scal,part,out);
}

// Round 3
// 253.283 us; speedup vs baseline: 1.3424x; 1.1940x over previous
//
#include <hip/hip_runtime.h>
#include <math.h>

#define NATOM 20000
#define NNBR  64
#define KM    64
#define KM3   (KM*KM*KM)

#define ALPHA_C 0.35f
#define KE_C    14.399645478425668f
#define TWO_OVER_SQRTPI 1.1283791670955126f
#define TWOPI_F 6.2831853071795864f
#define PI_F    3.14159265358979f
#define RC2     661.2244898f   /* (9/alpha)^2 : erfc(9)~4e-37 beyond */

// scal layout (floats)
#define S_V     0
#define S_QTOT  1
#define S_SUMQ2 2
#define S_HINV  3   // 3..11 row-major inv(cell)
#define S_NSCAL 16

// workspace layout (float offsets)
#define WS_RE    0
#define WS_IM    (KM3)
#define WS_MESH  (2*KM3)
#define WS_FI    (3*KM3)                  // 3*NATOM, plain-stored (no init needed)
#define WS_GJ    (WS_FI + 3*NATOM)        // 3*NATOM, atomic scatter target (zeroed)
#define WS_SCAL  (WS_GJ + 3*NATOM)
#define WS_CFAC  (WS_SCAL + S_NSCAL)
#define WS_PART  (WS_CFAC + KM)           // 64 slots * 16 fields (zeroed)
#define WS_TOTAL (WS_PART + 64*16)
// part fields: 0=e_real, 1..6=geps_real(xx,yy,zz,xy,xz,yz), 7=sE_rec, 8..13=sV

__device__ __forceinline__ float M2f(float x){ return fmaxf(0.f, 1.f - fabsf(x - 1.f)); }
__device__ __forceinline__ float M3f(float x){ return (x*M2f(x) + (3.f-x)*M2f(x-1.f)) * 0.5f; }
__device__ __forceinline__ float M4f(float x){ return (x*M3f(x) + (4.f-x)*M3f(x-1.f)) * (1.f/3.f); }

__device__ __forceinline__ float wsum64(float v){
#pragma unroll
  for(int off=32; off>0; off>>=1) v += __shfl_xor(v, off, 64);
  return v;
}

// ---------------- setup: Hinv, V, qtot, sum q^2, B-spline |b(m)|^-2 table ----
__global__ void setup_kernel(const float* __restrict__ q, const float* __restrict__ cell,
                             float* __restrict__ scal, float* __restrict__ cfac){
  __shared__ float s1[256], s2[256];
  int t = threadIdx.x;
  float a=0.f, b=0.f;
  for(int i=t;i<NATOM;i+=256){ float qi=q[i]; a+=qi; b+=qi*qi; }
  s1[t]=a; s2[t]=b; __syncthreads();
  for(int off=128; off>0; off>>=1){ if(t<off){ s1[t]+=s1[t+off]; s2[t]+=s2[t+off]; } __syncthreads(); }
  if(t==0){
    scal[S_QTOT]=s1[0]; scal[S_SUMQ2]=s2[0];
    float m00=cell[0],m01=cell[1],m02=cell[2];
    float m10=cell[3],m11=cell[4],m12=cell[5];
    float m20=cell[6],m21=cell[7],m22=cell[8];
    float det = m00*(m11*m22-m12*m21) - m01*(m10*m22-m12*m20) + m02*(m10*m21-m11*m20);
    float id = 1.f/det;
    scal[S_V] = fabsf(det);
    scal[S_HINV+0] = (m11*m22 - m12*m21)*id;
    scal[S_HINV+1] = (m02*m21 - m01*m22)*id;
    scal[S_HINV+2] = (m01*m12 - m02*m11)*id;
    scal[S_HINV+3] = (m12*m20 - m10*m22)*id;
    scal[S_HINV+4] = (m00*m22 - m02*m20)*id;
    scal[S_HINV+5] = (m02*m10 - m00*m12)*id;
    scal[S_HINV+6] = (m10*m21 - m11*m20)*id;
    scal[S_HINV+7] = (m01*m20 - m00*m21)*id;
    scal[S_HINV+8] = (m00*m11 - m01*m10)*id;
  }
  if(t < KM){
    const float Mv[3] = {1.f/6.f, 2.f/3.f, 1.f/6.f};
    float dre=0.f, dim=0.f;
#pragma unroll
    for(int k=0;k<3;k++){
      float ph = TWOPI_F * (float)t * (float)k / (float)KM;
      float s_, c_; sincosf(ph, &s_, &c_);
      dre += Mv[k]*c_; dim += Mv[k]*s_;
    }
    cfac[t] = 1.f/(dre*dre + dim*dim);
  }
}

// ---------------- real-space pair sum: grid-stride waves, 4 atoms/wave ------
__global__ __launch_bounds__(256) void real_kernel(
    const float* __restrict__ pos, const float* __restrict__ q,
    const int* __restrict__ nbr, const int* __restrict__ shifts,
    const float* __restrict__ cell,
    float* __restrict__ fi, float* __restrict__ gj, float* __restrict__ part){
  int lane = threadIdx.x & 63;
  int wid  = blockIdx.x*4 + (threadIdx.x>>6);
  float c0=cell[0],c1=cell[1],c2=cell[2];
  float c3=cell[3],c4=cell[4],c5=cell[5];
  float c6=cell[6],c7=cell[7],c8=cell[8];
  float e=0.f, vxx=0.f,vyy=0.f,vzz=0.f,vxy=0.f,vxz=0.f,vyz=0.f;
#pragma unroll
  for(int it=0; it<4; ++it){
    int i = wid*4 + it;
    float xi=pos[3*i], yi=pos[3*i+1], zi=pos[3*i+2], qi=q[i];
    int p = i*NNBR + lane;
    int j = nbr[p];
    int sx=shifts[3*p], sy=shifts[3*p+1], sz=shifts[3*p+2];
    bool self = (j==i) && (sx==0) && (sy==0) && (sz==0);
    float s=0.f, rx=0.f, ry=0.f, rz=0.f;
    if(j>=0 && !self){
      rx = pos[3*j]   - xi + sx*c0 + sy*c3 + sz*c6;
      ry = pos[3*j+1] - yi + sx*c1 + sy*c4 + sz*c7;
      rz = pos[3*j+2] - zi + sx*c2 + sy*c5 + sz*c8;
      float r2 = rx*rx + ry*ry + rz*rz;
      if(r2 > 0.f && r2 < RC2){
        float r = sqrtf(r2);
        float ar = ALPHA_C * r;
        float qq = qi * q[j];
        float ef = erfcf(ar);
        float ex = expf(-ar*ar);
        float ir = 1.f/r;
        e += 0.5f*qq*ef*ir;
        s  = 0.5f*qq*(ef + TWO_OVER_SQRTPI*ar*ex)*ir*ir*ir;
      }
    }
    float gx = s*rx, gy = s*ry, gz = s*rz;
    if(s != 0.f){
      unsafeAtomicAdd(&gj[3*j+0], -gx);
      unsafeAtomicAdd(&gj[3*j+1], -gy);
      unsafeAtomicAdd(&gj[3*j+2], -gz);
    }
    vxx -= s*rx*rx; vyy -= s*ry*ry; vzz -= s*rz*rz;
    vxy -= s*rx*ry; vxz -= s*rx*rz; vyz -= s*ry*rz;
    float tgx = wsum64(gx), tgy = wsum64(gy), tgz = wsum64(gz);
    if(lane==0){ fi[3*i]=tgx; fi[3*i+1]=tgy; fi[3*i+2]=tgz; }
  }
  e   = wsum64(e);
  vxx = wsum64(vxx); vyy = wsum64(vyy); vzz = wsum64(vzz);
  vxy = wsum64(vxy); vxz = wsum64(vxz); vyz = wsum64(vyz);
  if(lane==0){
    float* slot = part + (wid & 63)*16;
    unsafeAtomicAdd(&slot[0], e);
    unsafeAtomicAdd(&slot[1], vxx); unsafeAtomicAdd(&slot[2], vyy); unsafeAtomicAdd(&slot[3], vzz);
    unsafeAtomicAdd(&slot[4], vxy); unsafeAtomicAdd(&slot[5], vxz); unsafeAtomicAdd(&slot[6], vyz);
  }
}

// ---------------- B-spline spreading: one wave per atom, one lane per point -
__global__ __launch_bounds__(256) void spread_kernel(
    const float* __restrict__ pos, const float* __restrict__ q,
    const float* __restrict__ scal, float* __restrict__ mesh){
  int wid  = blockIdx.x*4 + (threadIdx.x>>6);   // atom index, grid covers exactly
  int lane = threadIdx.x & 63;
  if(wid >= NATOM) return;
  float h0=scal[S_HINV+0],h1=scal[S_HINV+1],h2=scal[S_HINV+2];
  float h3=scal[S_HINV+3],h4=scal[S_HINV+4],h5=scal[S_HINV+5];
  float h6=scal[S_HINV+6],h7=scal[S_HINV+7],h8=scal[S_HINV+8];
  float px=pos[3*wid], py=pos[3*wid+1], pz=pos[3*wid+2], qi=q[wid];
  float u0=(px*h0+py*h3+pz*h6)*(float)KM;
  float u1=(px*h1+py*h4+pz*h7)*(float)KM;
  float u2=(px*h2+py*h5+pz*h8)*(float)KM;
  float b0=floorf(u0), b1=floorf(u1), b2=floorf(u2);
  float t0=u0-b0, t1=u1-b1, t2=u2-b2;
  int i0=(int)b0, i1=(int)b1, i2=(int)b2;
  int a = lane>>4, b = (lane>>2)&3, c = lane&3;
  float w = qi * M4f(t0+(float)a) * M4f(t1+(float)b) * M4f(t2+(float)c);
  int ix=(i0-a+256)&63, iy=(i1-b+256)&63, iz=(i2-c+256)&63;
  unsafeAtomicAdd(&mesh[(ix*KM + iy)*KM + iz], w);
}

// ---------------- DFT along z: 4 contiguous lines per 256-block -------------
__global__ __launch_bounds__(256) void dft_z(const float* __restrict__ srcr,
                       float* __restrict__ re, float* __restrict__ im, float sgn){
  __shared__ float tr[4][64], ti[4][64], twr[64], twi[64];
  int t = threadIdx.x;
  if(t < 64){
    float ss, cc; sincosf(sgn*(TWOPI_F/64.f)*(float)t, &ss, &cc);
    twr[t]=cc; twi[t]=ss;
  }
  int base = blockIdx.x*256;
  int line = t>>6, p = t&63;
  if(srcr){ tr[line][p]=srcr[base+t]; ti[line][p]=0.f; }
  else    { tr[line][p]=re[base+t];   ti[line][p]=im[base+t]; }
  __syncthreads();
  float ar=0.f, ai=0.f;
#pragma unroll 8
  for(int z=0; z<64; z++){
    int k = (p*z)&63;
    float wr=twr[k], wi=twi[k], xr=tr[line][z], xi=ti[line][z];
    ar = fmaf(xr, wr, fmaf(-xi, wi, ar));
    ai = fmaf(xr, wi, fmaf( xi, wr, ai));
  }
  re[base+t]=ar; im[base+t]=ai;
}

// ---------------- DFT along x or y: 64x16 LDS tile, coalesced ---------------
__global__ __launch_bounds__(256) void dft_xy(float* __restrict__ re, float* __restrict__ im,
                                              int axis, float sgn){
  __shared__ float tr[64][17], ti[64][17], twr[64], twi[64];
  int t = threadIdx.x;
  if(t < 64){
    float ss, cc; sincosf(sgn*(TWOPI_F/64.f)*(float)t, &ss, &cc);
    twr[t]=cc; twi[t]=ss;
  }
  int stride = (axis==1) ? 64 : 4096;
  int base   = (axis==1) ? (int)(blockIdx.x>>2)*4096 + (int)(blockIdx.x&3)*16
                         : (int)(blockIdx.x>>2)*64   + (int)(blockIdx.x&3)*16;
#pragma unroll
  for(int k=0;k<4;k++){
    int e = k*256 + t;
    int li = e>>4, zz = e&15;
    int idx = base + li*stride + zz;
    tr[li][zz] = re[idx]; ti[li][zz] = im[idx];
  }
  __syncthreads();
#pragma unroll
  for(int k=0;k<4;k++){
    int e = k*256 + t;
    int lo = e>>4, zz = e&15;
    float ar=0.f, ai=0.f;
#pragma unroll 8
    for(int li=0; li<64; li++){
      int kk = (lo*li)&63;
      float wr=twr[kk], wi=twi[kk], xr=tr[li][zz], xi=ti[li][zz];
      ar = fmaf(xr, wr, fmaf(-xi, wi, ar));
      ai = fmaf(xr, wi, fmaf( xi, wr, ai));
    }
    int idx = base + lo*stride + zz;
    re[idx]=ar; im[idx]=ai;
  }
}

// ---------------- k-space multiply + energy/virial reduction ----------------
__global__ void kmul_kernel(float* __restrict__ re, float* __restrict__ im,
                            const float* __restrict__ scal, const float* __restrict__ cfac,
                            float* __restrict__ part){
  float h0=scal[S_HINV+0],h1=scal[S_HINV+1],h2=scal[S_HINV+2];
  float h3=scal[S_HINV+3],h4=scal[S_HINV+4],h5=scal[S_HINV+5];
  float h6=scal[S_HINV+6],h7=scal[S_HINV+7],h8=scal[S_HINV+8];
  const float a2 = ALPHA_C*ALPHA_C;
  const float inv4a2 = 1.f/(4.f*a2);
  float sE=0.f, v0=0.f,v1=0.f,v2=0.f,v3=0.f,v4=0.f,v5=0.f;
  for(int idx = blockIdx.x*blockDim.x + threadIdx.x; idx < KM3; idx += gridDim.x*blockDim.x){
    int mz = idx & 63, my = (idx>>6) & 63, mx = idx>>12;
    float fx = (float)(mx<32 ? mx : mx-64);
    float fy = (float)(my<32 ? my : my-64);
    float fz = (float)(mz<32 ? mz : mz-64);
    float kx = TWOPI_F*(fx*h0 + fy*h1 + fz*h2);
    float ky = TWOPI_F*(fx*h3 + fy*h4 + fz*h5);
    float kz = TWOPI_F*(fx*h6 + fy*h7 + fz*h8);
    float k2 = kx*kx + ky*ky + kz*kz;
    float qr = re[idx], qi = im[idx];
    float w = 0.f;
    if(k2 > 0.f){
      float kern = expf(-k2*inv4a2)/k2;
      w = kern * cfac[mx]*cfac[my]*cfac[mz];
      float q2 = qr*qr + qi*qi;
      sE += w*q2;
      float fac = w*q2*(inv4a2 + 1.f/k2)*2.f;
      v0 += fac*kx*kx; v1 += fac*ky*ky; v2 += fac*kz*kz;
      v3 += fac*kx*ky; v4 += fac*kx*kz; v5 += fac*ky*kz;
    }
    re[idx] = w*qr; im[idx] = w*qi;
  }
  __shared__ float red[256];
  float vals[7] = {sE, v0, v1, v2, v3, v4, v5};
  float out7[7];
#pragma unroll
  for(int k=0;k<7;k++){
    red[threadIdx.x] = vals[k]; __syncthreads();
    for(int off=128; off>0; off>>=1){ if(threadIdx.x<off) red[threadIdx.x]+=red[threadIdx.x+off]; __syncthreads(); }
    out7[k]=red[0]; __syncthreads();
  }
  if(threadIdx.x==0){
    float* slot = part + (blockIdx.x & 63)*16;
    unsafeAtomicAdd(&slot[7],  out7[0]);
#pragma unroll
    for(int k=0;k<6;k++) unsafeAtomicAdd(&slot[8+k], out7[1+k]);
  }
}

// ---------------- force gather: one wave per atom, one lane per point -------
__global__ __launch_bounds__(256) void gather_kernel(
    const float* __restrict__ pos, const float* __restrict__ q,
    const float* __restrict__ scal, const float* __restrict__ phi,
    const float* __restrict__ fi, const float* __restrict__ gj,
    float* __restrict__ out){
  int wid  = blockIdx.x*4 + (threadIdx.x>>6);
  int lane = threadIdx.x & 63;
  if(wid >= NATOM) return;
  float h0=scal[S_HINV+0],h1=scal[S_HINV+1],h2=scal[S_HINV+2];
  float h3=scal[S_HINV+3],h4=scal[S_HINV+4],h5=scal[S_HINV+5];
  float h6=scal[S_HINV+6],h7=scal[S_HINV+7],h8=scal[S_HINV+8];
  float V = scal[S_V];
  float px=pos[3*wid], py=pos[3*wid+1], pz=pos[3*wid+2], qi=q[wid];
  float u0=(px*h0+py*h3+pz*h6)*(float)KM;
  float u1=(px*h1+py*h4+pz*h7)*(float)KM;
  float u2=(px*h2+py*h5+pz*h8)*(float)KM;
  float b0=floorf(u0), b1=floorf(u1), b2=floorf(u2);
  float t0=u0-b0, t1=u1-b1, t2=u2-b2;
  int i0=(int)b0, i1=(int)b1, i2=(int)b2;
  int a = lane>>4, b = (lane>>2)&3, c = lane&3;
  float fa=(float)a, fb=(float)b, fc=(float)c;
  float wxa=M4f(t0+fa), wyb=M4f(t1+fb), wzc=M4f(t2+fc);
  float dxa=M3f(t0+fa)-M3f(t0+fa-1.f);
  float dyb=M3f(t1+fb)-M3f(t1+fb-1.f);
  float dzc=M3f(t2+fc)-M3f(t2+fc-1.f);
  int ix=(i0-a+256)&63, iy=(i1-b+256)&63, iz=(i2-c+256)&63;
  float p = phi[(ix*KM + iy)*KM + iz];
  float Sx = wsum64(p*dxa*wyb*wzc);
  float Sy = wsum64(p*wxa*dyb*wzc);
  float Sz = wsum64(p*wxa*wyb*dzc);
  if(lane==0){
    float scale = qi * (2.f*TWOPI_F/V) * (float)KM;
    float g0 = scale*(Sx*h0 + Sy*h1 + Sz*h2);
    float g1 = scale*(Sx*h3 + Sy*h4 + Sz*h5);
    float g2 = scale*(Sx*h6 + Sy*h7 + Sz*h8);
    out[1+3*wid+0] = -KE_C*(fi[3*wid+0] + gj[3*wid+0] + g0);
    out[1+3*wid+1] = -KE_C*(fi[3*wid+1] + gj[3*wid+1] + g1);
    out[1+3*wid+2] = -KE_C*(fi[3*wid+2] + gj[3*wid+2] + g2);
  }
}

// ---------------- finalize: energy + stress ---------------------------------
__global__ void finalize_kernel(const float* __restrict__ scal, const float* __restrict__ part,
                                float* __restrict__ out){
  if(threadIdx.x!=0 || blockIdx.x!=0) return;
  float acc[14];
  for(int k=0;k<14;k++) acc[k]=0.f;
  for(int s=0;s<64;s++)
    for(int k=0;k<14;k++) acc[k] += part[s*16+k];
  float V = scal[S_V], qtot = scal[S_QTOT], sumq2 = scal[S_SUMQ2];
  float a2 = ALPHA_C*ALPHA_C;
  float pref = TWOPI_F/V;
  float e_real = acc[0];
  float e_rec  = pref*acc[7];
  float e_self = -(ALPHA_C/sqrtf(PI_F))*sumq2;
  float e_bg   = -(PI_F/(2.f*a2*V))*qtot*qtot;
  out[0] = (e_real + e_rec + e_self + e_bg)*KE_C;
  float vs0=pref*acc[8], vs1=pref*acc[9], vs2=pref*acc[10];
  float vs3=pref*acc[11], vs4=pref*acc[12], vs5=pref*acc[13];
  float gxx = acc[1] + vs0 - e_rec - e_bg;
  float gyy = acc[2] + vs1 - e_rec - e_bg;
  float gzz = acc[3] + vs2 - e_rec - e_bg;
  float gxy = acc[4] + vs3, gxz = acc[5] + vs4, gyz = acc[6] + vs5;
  float c = -KE_C/V;    // stress = virial/V = -geps*KE/V
  float* st = out + 1 + 3*NATOM;
  st[0]=c*gxx; st[4]=c*gyy; st[8]=c*gzz;
  st[1]=c*gxy; st[3]=c*gxy;
  st[2]=c*gxz; st[6]=c*gxz;
  st[5]=c*gyz; st[7]=c*gyz;
}

extern "C" void kernel_launch(void* const* d_in, const int* in_sizes, int n_in,
                              void* d_out, int out_size, void* d_ws, size_t ws_size,
                              hipStream_t stream) {
  const float* pos  = (const float*)d_in[0];
  const float* q    = (const float*)d_in[1];
  const float* cell = (const float*)d_in[2];
  const int* nbr    = (const int*)d_in[3];
  const int* shifts = (const int*)d_in[4];
  float* out = (float*)d_out;
  float* ws  = (float*)d_ws;
  float* bufRe = ws + WS_RE;
  float* bufIm = ws + WS_IM;
  float* mesh  = ws + WS_MESH;
  float* fi    = ws + WS_FI;
  float* gj    = ws + WS_GJ;
  float* scal  = ws + WS_SCAL;
  float* cfac  = ws + WS_CFAC;
  float* part  = ws + WS_PART;

  // zero mesh, fi, gj, scal, cfac, part in one contiguous memset
  hipMemsetAsync(mesh, 0, (size_t)(WS_TOTAL - WS_MESH)*sizeof(float), stream);
  setup_kernel<<<1,256,0,stream>>>(q, cell, scal, cfac);
  real_kernel<<<1250,256,0,stream>>>(pos,q,nbr,shifts,cell,fi,gj,part);
  spread_kernel<<<5000,256,0,stream>>>(pos,q,scal,mesh);
  dft_z <<<1024,256,0,stream>>>(mesh, bufRe, bufIm, -1.f);
  dft_xy<<< 256,256,0,stream>>>(bufRe, bufIm, 1, -1.f);
  dft_xy<<< 256,256,0,stream>>>(bufRe, bufIm, 0, -1.f);
  kmul_kernel<<<256,256,0,stream>>>(bufRe,bufIm,scal,cfac,part);
  dft_xy<<< 256,256,0,stream>>>(bufRe, bufIm, 0,  1.f);
  dft_xy<<< 256,256,0,stream>>>(bufRe, bufIm, 1,  1.f);
  dft_z <<<1024,256,0,stream>>>(nullptr, bufRe, bufIm, 1.f);
  gather_kernel<<<5000,256,0,stream>>>(pos,q,scal,bufRe,fi,gj,out);
  finalize_kernel<<<1,1,0,stream>>>(scal,part,out);
}

// Round 4
// 191.226 us; speedup vs baseline: 1.7780x; 1.3245x over previous
//
#include <hip/hip_runtime.h>
#include <math.h>

#define NATOM 20000
#define NNBR  64
#define KM    64
#define KM3   (KM*KM*KM)

#define ALPHA_C 0.35f
#define KE_C    14.399645478425668f
#define TWO_OVER_SQRTPI 1.1283791670955126f
#define TWOPI_F 6.2831853071795864f
#define PI_F    3.14159265358979f
#define RC2     661.2244898f   /* (9/alpha)^2 */

// workspace layout (float offsets)
#define WS_RE    0
#define WS_IM    (KM3)
#define WS_MESH  (2*KM3)                  // zeroed ----
#define WS_GJ    (3*KM3)                  // 3*NATOM, zeroed
#define WS_PART  (3*KM3 + 3*NATOM)        // 64 slots * 16 fields, zeroed ----
#define WS_FI    (WS_PART + 1024)         // 3*NATOM, plain-stored
#define WS_POSQ  (WS_FI + 3*NATOM)        // 4*NATOM (float4, 16B-aligned)
#define ZERO_LEN (KM3 + 3*NATOM + 1024)
// part fields: 0=e_real, 1..6=geps_real(xx,yy,zz,xy,xz,yz), 7=sE_rec, 8..13=sV

__device__ __forceinline__ float M2f(float x){ return fmaxf(0.f, 1.f - fabsf(x - 1.f)); }
__device__ __forceinline__ float M3f(float x){ return (x*M2f(x) + (3.f-x)*M2f(x-1.f)) * 0.5f; }
__device__ __forceinline__ float M4f(float x){ return (x*M3f(x) + (4.f-x)*M3f(x-1.f)) * (1.f/3.f); }

__device__ __forceinline__ float wsum64(float v){
#pragma unroll
  for(int off=32; off>0; off>>=1) v += __shfl_xor(v, off, 64);
  return v;
}

// 3x3 inverse of row-major cell; returns |det|
__device__ __forceinline__ float hinv9(const float* __restrict__ cell, float* h){
  float m00=cell[0],m01=cell[1],m02=cell[2];
  float m10=cell[3],m11=cell[4],m12=cell[5];
  float m20=cell[6],m21=cell[7],m22=cell[8];
  float det = m00*(m11*m22-m12*m21) - m01*(m10*m22-m12*m20) + m02*(m10*m21-m11*m20);
  float id = 1.f/det;
  h[0]=(m11*m22-m12*m21)*id; h[1]=(m02*m21-m01*m22)*id; h[2]=(m01*m12-m02*m11)*id;
  h[3]=(m12*m20-m10*m22)*id; h[4]=(m00*m22-m02*m20)*id; h[5]=(m02*m10-m00*m12)*id;
  h[6]=(m10*m21-m11*m20)*id; h[7]=(m01*m20-m00*m21)*id; h[8]=(m00*m11-m01*m10)*id;
  return fabsf(det);
}

// ---- in-register 64-point DFT across the wave: lane l holds x[l] ----------
// Computes X[k] = sum_n x[n] e^{sgn*2*pi*i*n*k/64}; result in natural order.
__device__ __forceinline__ void fft64(float& xr, float& xi, int lane, float sgn8){
#pragma unroll
  for(int k=0;k<6;k++){
    int half = 32 >> k;
    float or_ = __shfl_xor(xr, half, 64);
    float oi_ = __shfl_xor(xi, half, 64);
    bool hi = (lane & half) != 0;
    float sr = hi ? (or_ - xr) : (xr + or_);
    float si = hi ? (oi_ - xi) : (xi + oi_);
    int e = (lane & (half-1)) << k;      // twiddle exponent, < 32
    float ws, wc; sincosf(sgn8 * (float)e, &ws, &wc);
    float wr2 = hi ? wc : 1.f;
    float wi2 = hi ? ws : 0.f;
    xr = sr*wr2 - si*wi2;
    xi = sr*wi2 + si*wr2;
  }
  int rev = __brev((unsigned)lane) >> 26;  // 6-bit bit-reverse
  xr = __shfl(xr, rev, 64);
  xi = __shfl(xi, rev, 64);
}

// ---------------- init: zero mesh/gj/part + pack posq -----------------------
__global__ __launch_bounds__(256) void init_kernel(
    const float* __restrict__ pos, const float* __restrict__ q,
    float* __restrict__ zbase, float4* __restrict__ posq){
  int t = blockIdx.x*256 + threadIdx.x;
  if(t < ZERO_LEN) zbase[t] = 0.f;
  if(t < NATOM)
    posq[t] = make_float4(pos[3*t], pos[3*t+1], pos[3*t+2], q[t]);
}

// ---------------- real-space pair sum: 4 atoms per wave ---------------------
__global__ __launch_bounds__(256) void real_kernel(
    const float4* __restrict__ posq,
    const int* __restrict__ nbr, const int* __restrict__ shifts,
    const float* __restrict__ cell,
    float* __restrict__ fi, float* __restrict__ gj, float* __restrict__ part){
  int lane = threadIdx.x & 63;
  int wid  = blockIdx.x*4 + (threadIdx.x>>6);
  float c0=cell[0],c1=cell[1],c2=cell[2];
  float c3=cell[3],c4=cell[4],c5=cell[5];
  float c6=cell[6],c7=cell[7],c8=cell[8];
  float e=0.f, vxx=0.f,vyy=0.f,vzz=0.f,vxy=0.f,vxz=0.f,vyz=0.f;
#pragma unroll
  for(int it=0; it<4; ++it){
    int i = wid*4 + it;
    float4 pi4 = posq[i];
    int p = i*NNBR + lane;
    int j = nbr[p];
    int sx=shifts[3*p], sy=shifts[3*p+1], sz=shifts[3*p+2];
    bool self = (j==i) && (sx==0) && (sy==0) && (sz==0);
    float s=0.f, rx=0.f, ry=0.f, rz=0.f;
    if(j>=0 && !self){
      float4 pj = posq[j];
      rx = pj.x - pi4.x + sx*c0 + sy*c3 + sz*c6;
      ry = pj.y - pi4.y + sx*c1 + sy*c4 + sz*c7;
      rz = pj.z - pi4.z + sx*c2 + sy*c5 + sz*c8;
      float r2 = rx*rx + ry*ry + rz*rz;
      if(r2 > 0.f && r2 < RC2){
        float r = sqrtf(r2);
        float ar = ALPHA_C * r;
        float qq = pi4.w * pj.w;
        float ef = erfcf(ar);
        float ex = expf(-ar*ar);
        float ir = 1.f/r;
        e += 0.5f*qq*ef*ir;
        s  = 0.5f*qq*(ef + TWO_OVER_SQRTPI*ar*ex)*ir*ir*ir;
      }
    }
    float gx = s*rx, gy = s*ry, gz = s*rz;
    if(s != 0.f){
      unsafeAtomicAdd(&gj[3*j+0], -gx);
      unsafeAtomicAdd(&gj[3*j+1], -gy);
      unsafeAtomicAdd(&gj[3*j+2], -gz);
    }
    vxx -= s*rx*rx; vyy -= s*ry*ry; vzz -= s*rz*rz;
    vxy -= s*rx*ry; vxz -= s*rx*rz; vyz -= s*ry*rz;
    float tgx = wsum64(gx), tgy = wsum64(gy), tgz = wsum64(gz);
    if(lane==0){ fi[3*i]=tgx; fi[3*i+1]=tgy; fi[3*i+2]=tgz; }
  }
  e   = wsum64(e);
  vxx = wsum64(vxx); vyy = wsum64(vyy); vzz = wsum64(vzz);
  vxy = wsum64(vxy); vxz = wsum64(vxz); vyz = wsum64(vyz);
  if(lane==0){
    float* slot = part + (wid & 63)*16;
    unsafeAtomicAdd(&slot[0], e);
    unsafeAtomicAdd(&slot[1], vxx); unsafeAtomicAdd(&slot[2], vyy); unsafeAtomicAdd(&slot[3], vzz);
    unsafeAtomicAdd(&slot[4], vxy); unsafeAtomicAdd(&slot[5], vxz); unsafeAtomicAdd(&slot[6], vyz);
  }
}

// ---------------- B-spline spreading: one wave/atom, one lane/point ---------
__global__ __launch_bounds__(256) void spread_kernel(
    const float4* __restrict__ posq, const float* __restrict__ cell,
    float* __restrict__ mesh){
  int wid  = blockIdx.x*4 + (threadIdx.x>>6);
  int lane = threadIdx.x & 63;
  float h[9]; hinv9(cell, h);
  float4 pq = posq[wid];
  float u0=(pq.x*h[0]+pq.y*h[3]+pq.z*h[6])*(float)KM;
  float u1=(pq.x*h[1]+pq.y*h[4]+pq.z*h[7])*(float)KM;
  float u2=(pq.x*h[2]+pq.y*h[5]+pq.z*h[8])*(float)KM;
  float b0=floorf(u0), b1=floorf(u1), b2=floorf(u2);
  float t0=u0-b0, t1=u1-b1, t2=u2-b2;
  int i0=(int)b0, i1=(int)b1, i2=(int)b2;
  int a = lane>>4, b = (lane>>2)&3, c = lane&3;
  float w = pq.w * M4f(t0+(float)a) * M4f(t1+(float)b) * M4f(t2+(float)c);
  int ix=(i0-a+256)&63, iy=(i1-b+256)&63, iz=(i2-c+256)&63;
  unsafeAtomicAdd(&mesh[(ix*KM + iy)*KM + iz], w);
}

// ---------------- fftA: forward z then y, one x-slab per block --------------
__global__ __launch_bounds__(256) void fftA(const float* __restrict__ mesh,
                                            float* __restrict__ re, float* __restrict__ im){
  __shared__ float lr[64][65], li[64][65];
  int t = threadIdx.x, lane = t&63, w = t>>6;
  int x = blockIdx.x;
  const float sgn8 = -(TWOPI_F/64.f);
  const float* mp = mesh + x*4096;
  // z-lines (y fixed): coalesced direct load, im=0
#pragma unroll
  for(int qq=0; qq<16; qq++){
    int y = w*16 + qq;
    float xr = mp[y*64 + lane], xi = 0.f;
    fft64(xr, xi, lane, sgn8);
    lr[y][lane]=xr; li[y][lane]=xi;
  }
  __syncthreads();
  // y-lines (z fixed): lane indexes y
#pragma unroll
  for(int qq=0; qq<16; qq++){
    int z = w*16 + qq;
    float xr = lr[lane][z], xi = li[lane][z];
    fft64(xr, xi, lane, sgn8);
    lr[lane][z]=xr; li[lane][z]=xi;
  }
  __syncthreads();
  float* rp = re + x*4096; float* ip = im + x*4096;
#pragma unroll
  for(int k=0;k<16;k++){
    int e = k*256 + t;
    rp[e]=lr[e>>6][e&63]; ip[e]=li[e>>6][e&63];
  }
}

// ---------------- fftB: forward x + k-space multiply + energy/virial --------
__global__ __launch_bounds__(256) void fftB(float* __restrict__ re, float* __restrict__ im,
                                            const float* __restrict__ cell,
                                            float* __restrict__ part){
  __shared__ float lr[64][17], li[64][17], cf[64];
  int t = threadIdx.x, lane = t&63, w = t>>6;
  int y = blockIdx.x>>2, z0 = (blockIdx.x&3)*16;
  const float sgn8 = -(TWOPI_F/64.f);
  float h[9]; hinv9(cell, h);
  if(t < 64){
    float p1 = TWOPI_F*(float)t/64.f;
    float s1,c1_,s2,c2_; sincosf(p1,&s1,&c1_); sincosf(2.f*p1,&s2,&c2_);
    float dre = (1.f/6.f) + (2.f/3.f)*c1_ + (1.f/6.f)*c2_;
    float dim = (2.f/3.f)*s1 + (1.f/6.f)*s2;
    cf[t] = 1.f/(dre*dre + dim*dim);
  }
  float* rp = re + y*64 + z0;
  float* ip = im + y*64 + z0;
#pragma unroll
  for(int k=0;k<4;k++){
    int e = k*256 + t; int xI = e>>4, zz = e&15;
    lr[xI][zz] = rp[xI*4096 + zz];
    li[xI][zz] = ip[xI*4096 + zz];
  }
  __syncthreads();
  const float inv4a2 = 1.f/(4.f*ALPHA_C*ALPHA_C);
  float my_f = (float)((y<32)? y : y-64);
  float sE=0.f, v0=0.f,v1=0.f,v2=0.f,v3=0.f,v4=0.f,v5=0.f;
#pragma unroll
  for(int qq=0; qq<4; qq++){
    int zz = w*4 + qq; int z = z0 + zz;
    float xr = lr[lane][zz], xi = li[lane][zz];
    fft64(xr, xi, lane, sgn8);       // lane = mx
    int mx = lane, mz = z;
    float fx = (float)((mx<32)? mx : mx-64);
    float fz = (float)((mz<32)? mz : mz-64);
    float kx = TWOPI_F*(fx*h[0] + my_f*h[1] + fz*h[2]);
    float ky = TWOPI_F*(fx*h[3] + my_f*h[4] + fz*h[5]);
    float kz = TWOPI_F*(fx*h[6] + my_f*h[7] + fz*h[8]);
    float k2 = kx*kx + ky*ky + kz*kz;
    float wk = 0.f;
    if(k2 > 0.f){
      float kern = expf(-k2*inv4a2)/k2;
      wk = kern * cf[mx]*cf[y]*cf[z];
      float q2 = xr*xr + xi*xi;
      sE += wk*q2;
      float fac = wk*q2*(inv4a2 + 1.f/k2)*2.f;
      v0 += fac*kx*kx; v1 += fac*ky*ky; v2 += fac*kz*kz;
      v3 += fac*kx*ky; v4 += fac*kx*kz; v5 += fac*ky*kz;
    }
    lr[lane][zz] = wk*xr; li[lane][zz] = wk*xi;
  }
  __syncthreads();
#pragma unroll
  for(int k=0;k<4;k++){
    int e = k*256 + t; int xI = e>>4, zz = e&15;
    rp[xI*4096 + zz] = lr[xI][zz];
    ip[xI*4096 + zz] = li[xI][zz];
  }
  sE = wsum64(sE);
  v0 = wsum64(v0); v1 = wsum64(v1); v2 = wsum64(v2);
  v3 = wsum64(v3); v4 = wsum64(v4); v5 = wsum64(v5);
  if(lane==0){
    float* slot = part + (((blockIdx.x<<2)|w)&63)*16;
    unsafeAtomicAdd(&slot[7],  sE);
    unsafeAtomicAdd(&slot[8],  v0); unsafeAtomicAdd(&slot[9],  v1);
    unsafeAtomicAdd(&slot[10], v2); unsafeAtomicAdd(&slot[11], v3);
    unsafeAtomicAdd(&slot[12], v4); unsafeAtomicAdd(&slot[13], v5);
  }
}

// ---------------- fftC: inverse x ------------------------------------------
__global__ __launch_bounds__(256) void fftC(float* __restrict__ re, float* __restrict__ im){
  __shared__ float lr[64][17], li[64][17];
  int t = threadIdx.x, lane = t&63, w = t>>6;
  int y = blockIdx.x>>2, z0 = (blockIdx.x&3)*16;
  const float sgn8 = (TWOPI_F/64.f);
  float* rp = re + y*64 + z0;
  float* ip = im + y*64 + z0;
#pragma unroll
  for(int k=0;k<4;k++){
    int e = k*256 + t; int xI = e>>4, zz = e&15;
    lr[xI][zz] = rp[xI*4096 + zz];
    li[xI][zz] = ip[xI*4096 + zz];
  }
  __syncthreads();
#pragma unroll
  for(int qq=0; qq<4; qq++){
    int zz = w*4 + qq;
    float xr = lr[lane][zz], xi = li[lane][zz];
    fft64(xr, xi, lane, sgn8);
    lr[lane][zz] = xr; li[lane][zz] = xi;
  }
  __syncthreads();
#pragma unroll
  for(int k=0;k<4;k++){
    int e = k*256 + t; int xI = e>>4, zz = e&15;
    rp[xI*4096 + zz] = lr[xI][zz];
    ip[xI*4096 + zz] = li[xI][zz];
  }
}

// ---------------- fftD: inverse y then z, write real part (phi) -------------
__global__ __launch_bounds__(256) void fftD(float* __restrict__ re, float* __restrict__ im){
  __shared__ float lr[64][65], li[64][65];
  int t = threadIdx.x, lane = t&63, w = t>>6;
  int x = blockIdx.x;
  const float sgn8 = (TWOPI_F/64.f);
  float* rp = re + x*4096;
  float* ip = im + x*4096;
#pragma unroll
  for(int k=0;k<16;k++){
    int e = k*256 + t;
    lr[e>>6][e&63] = rp[e];
    li[e>>6][e&63] = ip[e];
  }
  __syncthreads();
  // y-lines (z fixed): lane indexes y
#pragma unroll
  for(int qq=0; qq<16; qq++){
    int z = w*16 + qq;
    float xr = lr[lane][z], xi = li[lane][z];
    fft64(xr, xi, lane, sgn8);
    lr[lane][z]=xr; li[lane][z]=xi;
  }
  __syncthreads();
  // z-lines (y fixed): lane indexes z; store re directly (coalesced)
#pragma unroll
  for(int qq=0; qq<16; qq++){
    int y = w*16 + qq;
    float xr = lr[y][lane], xi = li[y][lane];
    fft64(xr, xi, lane, sgn8);
    rp[y*64 + lane] = xr;
  }
}

// ---------------- gather + merged finalize ----------------------------------
__global__ __launch_bounds__(256) void gather_kernel(
    const float4* __restrict__ posq, const float* __restrict__ cell,
    const float* __restrict__ phi,
    const float* __restrict__ fi, const float* __restrict__ gj,
    const float* __restrict__ part, float* __restrict__ out){
  __shared__ float sa[256], sb[256], facc[16];
  int wid  = blockIdx.x*4 + (threadIdx.x>>6);
  int lane = threadIdx.x & 63;
  float h[9]; float V = hinv9(cell, h);
  float4 pq = posq[wid];
  float u0=(pq.x*h[0]+pq.y*h[3]+pq.z*h[6])*(float)KM;
  float u1=(pq.x*h[1]+pq.y*h[4]+pq.z*h[7])*(float)KM;
  float u2=(pq.x*h[2]+pq.y*h[5]+pq.z*h[8])*(float)KM;
  float b0=floorf(u0), b1=floorf(u1), b2=floorf(u2);
  float t0=u0-b0, t1=u1-b1, t2=u2-b2;
  int i0=(int)b0, i1=(int)b1, i2=(int)b2;
  int a = lane>>4, b = (lane>>2)&3, c = lane&3;
  float fa=(float)a, fb=(float)b, fc=(float)c;
  float wxa=M4f(t0+fa), wyb=M4f(t1+fb), wzc=M4f(t2+fc);
  float dxa=M3f(t0+fa)-M3f(t0+fa-1.f);
  float dyb=M3f(t1+fb)-M3f(t1+fb-1.f);
  float dzc=M3f(t2+fc)-M3f(t2+fc-1.f);
  int ix=(i0-a+256)&63, iy=(i1-b+256)&63, iz=(i2-c+256)&63;
  float p = phi[(ix*KM + iy)*KM + iz];
  float Sx = wsum64(p*dxa*wyb*wzc);
  float Sy = wsum64(p*wxa*dyb*wzc);
  float Sz = wsum64(p*wxa*wyb*dzc);
  if(lane==0){
    float scale = pq.w * (2.f*TWOPI_F/V) * (float)KM;
    float g0 = scale*(Sx*h[0] + Sy*h[1] + Sz*h[2]);
    float g1 = scale*(Sx*h[3] + Sy*h[4] + Sz*h[5]);
    float g2 = scale*(Sx*h[6] + Sy*h[7] + Sz*h[8]);
    out[1+3*wid+0] = -KE_C*(fi[3*wid+0] + gj[3*wid+0] + g0);
    out[1+3*wid+1] = -KE_C*(fi[3*wid+1] + gj[3*wid+1] + g1);
    out[1+3*wid+2] = -KE_C*(fi[3*wid+2] + gj[3*wid+2] + g2);
  }
  // ---- finalize (block 0 only): energy + stress ----
  if(blockIdx.x==0){
    int t = threadIdx.x;
    float qa=0.f, qb=0.f;
    for(int i=t;i<NATOM;i+=256){ float qv=posq[i].w; qa+=qv; qb+=qv*qv; }
    sa[t]=qa; sb[t]=qb; __syncthreads();
    for(int off=128; off>0; off>>=1){
      if(t<off){ sa[t]+=sa[t+off]; sb[t]+=sb[t+off]; } __syncthreads();
    }
    if(t<14){ float s=0.f; for(int sl=0;sl<64;sl++) s+=part[sl*16+t]; facc[t]=s; }
    __syncthreads();
    if(t==0){
      float qtot = sa[0], sumq2 = sb[0];
      float a2 = ALPHA_C*ALPHA_C;
      float pref = TWOPI_F/V;
      float e_real = facc[0];
      float e_rec  = pref*facc[7];
      float e_self = -(ALPHA_C/sqrtf(PI_F))*sumq2;
      float e_bg   = -(PI_F/(2.f*a2*V))*qtot*qtot;
      out[0] = (e_real + e_rec + e_self + e_bg)*KE_C;
      float gxx = facc[1] + pref*facc[8]  - e_rec - e_bg;
      float gyy = facc[2] + pref*facc[9]  - e_rec - e_bg;
      float gzz = facc[3] + pref*facc[10] - e_rec - e_bg;
      float gxy = facc[4] + pref*facc[11];
      float gxz = facc[5] + pref*facc[12];
      float gyz = facc[6] + pref*facc[13];
      float cc = -KE_C/V;
      float* st = out + 1 + 3*NATOM;
      st[0]=cc*gxx; st[4]=cc*gyy; st[8]=cc*gzz;
      st[1]=cc*gxy; st[3]=cc*gxy;
      st[2]=cc*gxz; st[6]=cc*gxz;
      st[5]=cc*gyz; st[7]=cc*gyz;
    }
  }
}

extern "C" void kernel_launch(void* const* d_in, const int* in_sizes, int n_in,
                              void* d_out, int out_size, void* d_ws, size_t ws_size,
                              hipStream_t stream) {
  const float* pos  = (const float*)d_in[0];
  const float* q    = (const float*)d_in[1];
  const float* cell = (const float*)d_in[2];
  const int* nbr    = (const int*)d_in[3];
  const int* shifts = (const int*)d_in[4];
  float* out = (float*)d_out;
  float* ws  = (float*)d_ws;
  float*  bufRe = ws + WS_RE;
  float*  bufIm = ws + WS_IM;
  float*  mesh  = ws + WS_MESH;
  float*  gj    = ws + WS_GJ;
  float*  part  = ws + WS_PART;
  float*  fi    = ws + WS_FI;
  float4* posq  = (float4*)(ws + WS_POSQ);

  init_kernel<<<(ZERO_LEN+255)/256,256,0,stream>>>(pos, q, mesh, posq);
  real_kernel<<<1250,256,0,stream>>>(posq, nbr, shifts, cell, fi, gj, part);
  spread_kernel<<<5000,256,0,stream>>>(posq, cell, mesh);
  fftA<<< 64,256,0,stream>>>(mesh, bufRe, bufIm);
  fftB<<<256,256,0,stream>>>(bufRe, bufIm, cell, part);
  fftC<<<256,256,0,stream>>>(bufRe, bufIm);
  fftD<<< 64,256,0,stream>>>(bufRe, bufIm);
  gather_kernel<<<5000,256,0,stream>>>(posq, cell, bufRe, fi, gj, part, out);
}